// Round 4
// baseline (167.779 us; speedup 1.0000x reference)
//
#include <hip/hip_runtime.h>
#include <hip/hip_fp16.h>

typedef _Float16 f16;
typedef __attribute__((ext_vector_type(8))) _Float16 f16x8;
typedef __attribute__((ext_vector_type(2))) _Float16 f16x2;
typedef __attribute__((ext_vector_type(16))) float f32x16;

#define B_SZ 16
#define T_SZ 2048
#define DIN 512
#define DOUT 512
#define N_SZ 512
#define M_SZ (B_SZ * T_SZ)  /* 32768 */
#define NCHUNK 16
#define LCHUNK 128          /* T_SZ / NCHUNK */

__device__ __forceinline__ void gload_lds16(const void* g, void* l) {
  __builtin_amdgcn_global_load_lds(
      (const __attribute__((address_space(1))) void*)g,
      (__attribute__((address_space(3))) void*)l, 16, 0, 0);
}

// ---------------- fused prep kernel (grid-range split) ----------------
// blocks [0,2): lam params; [2,2050): W1; [2050,5122): W2; [5122,13314): input->f16

__global__ void prep_all(const float* __restrict__ nu_log,
                         const float* __restrict__ theta_log,
                         const float* __restrict__ gamma_log,
                         const float* __restrict__ B_re, const float* __restrict__ B_im,
                         const float* __restrict__ C_re, const float* __restrict__ C_im,
                         const float* __restrict__ Dm, const float* __restrict__ input,
                         float2* __restrict__ lam2, float2* __restrict__ lamL2,
                         f16* __restrict__ W1, f16* __restrict__ W2,
                         f16* __restrict__ A2) {
  int b = blockIdx.x;
  if (b < 2) {
    int n = b * 256 + threadIdx.x;
    float nu = expf(nu_log[n]);
    float ph = expf(theta_log[n]);
    float la = expf(-nu);
    lam2[n] = make_float2(la * cosf(ph), la * sinf(ph));
    float laL = expf(-nu * (float)LCHUNK);
    float phL = ph * (float)LCHUNK;
    lamL2[n] = make_float2(laL * cosf(phL), laL * sinf(phL));
  } else if (b < 2 + 2048) {
    int tid = (b - 2) * 256 + threadIdx.x;   // 1024*512
    int np = tid >> 9;
    int d = tid & 511;
    int n = np >> 1;
    float g = expf(gamma_log[n]);
    const float* src = (np & 1) ? B_im : B_re;
    W1[(size_t)np * 512 + d] = (f16)(src[(size_t)n * 512 + d] * g);
  } else if (b < 2 + 2048 + 3072) {
    int tid = (b - 2050) * 256 + threadIdx.x;  // 512*1536
    int j = tid / 1536;
    int k = tid - j * 1536;
    float v;
    if (k < 512)       v =  C_re[(size_t)j * 512 + k];
    else if (k < 1024) v = -C_im[(size_t)j * 512 + (k - 512)];
    else               v =  Dm[(size_t)j * 512 + (k - 1024)];
    W2[(size_t)j * 1536 + k] = (f16)v;
  } else {
    int tid = (b - 5122) * 256 + threadIdx.x;  // 32768*512/8
    int m = tid >> 6;
    int d0 = (tid & 63) << 3;
    const float4* p = (const float4*)(input + (size_t)m * DIN + d0);
    float4 a = p[0], c = p[1];
    f16x8 h;
    h[0] = (f16)a.x; h[1] = (f16)a.y; h[2] = (f16)a.z; h[3] = (f16)a.w;
    h[4] = (f16)c.x; h[5] = (f16)c.y; h[6] = (f16)c.z; h[7] = (f16)c.w;
    *(f16x8*)(A2 + (size_t)m * 1536 + 1024 + d0) = h;
  }
}

// ---------------- scan (3 phases, fp32 math, f16 Bu) ----------------

__global__ void scan_a(const f16* __restrict__ Bu, const float2* __restrict__ lam2,
                       float2* __restrict__ S) {
  int tid = blockIdx.x * 256 + threadIdx.x;  // B*NCHUNK*N = 131072
  int n = tid & 511;
  int c = (tid >> 9) & (NCHUNK - 1);
  int b = tid >> 13;
  float2 l = lam2[n];
  const unsigned* bu = (const unsigned*)Bu + (size_t)(b * T_SZ + c * LCHUNK) * 512 + n;
  float sre = 0.f, sim = 0.f;
#pragma unroll 8
  for (int t = 0; t < LCHUNK; ++t) {
    unsigned u = bu[(size_t)t * 512];
    f16x2 h = __builtin_bit_cast(f16x2, u);
    float nre = l.x * sre - l.y * sim + (float)h.x;
    sim = l.x * sim + l.y * sre + (float)h.y;
    sre = nre;
  }
  S[(size_t)(b * NCHUNK + c) * 512 + n] = make_float2(sre, sim);
}

__global__ void scan_b(const float2* __restrict__ S, const float2* __restrict__ lamL2,
                       float2* __restrict__ Carry) {
  int tid = blockIdx.x * 256 + threadIdx.x;  // 8192
  int n = tid & 511;
  int b = tid >> 9;
  float2 lL = lamL2[n];
  float cre = 0.f, cim = 0.f;
  for (int c = 0; c < NCHUNK; ++c) {
    size_t idx = (size_t)(b * NCHUNK + c) * 512 + n;
    Carry[idx] = make_float2(cre, cim);
    float2 s = S[idx];
    float nre = lL.x * cre - lL.y * cim + s.x;
    cim = lL.x * cim + lL.y * cre + s.y;
    cre = nre;
  }
}

__global__ void scan_c(const f16* __restrict__ Bu, const float2* __restrict__ lam2,
                       const float2* __restrict__ Carry, f16* __restrict__ A2) {
  int tid = blockIdx.x * 256 + threadIdx.x;
  int n = tid & 511;
  int c = (tid >> 9) & (NCHUNK - 1);
  int b = tid >> 13;
  float2 l = lam2[n];
  float2 car = Carry[(size_t)(b * NCHUNK + c) * 512 + n];
  float sre = car.x, sim = car.y;
  int m0 = b * T_SZ + c * LCHUNK;
  const unsigned* bu = (const unsigned*)Bu + (size_t)m0 * 512 + n;
  f16* outre = A2 + (size_t)m0 * 1536 + n;
#pragma unroll 4
  for (int t = 0; t < LCHUNK; ++t) {
    unsigned u = bu[(size_t)t * 512];
    f16x2 h = __builtin_bit_cast(f16x2, u);
    float nre = l.x * sre - l.y * sim + (float)h.x;
    sim = l.x * sim + l.y * sre + (float)h.y;
    sre = nre;
    outre[(size_t)t * 1536] = (f16)sre;
    outre[(size_t)t * 1536 + 512] = (f16)sim;
  }
}

// ---------------- 256x256 8-wave ring-4 pipelined GEMM: C = A[M][K]*B[Nn][K]^T ----
// Granule = K=32 slice (A 256x32 + B 256x32 = 32 KB). Ring of 4 slots = 128 KiB.
// Phase g: vmcnt(4) [granule g's 4 loads are the OLDEST in flight -> landed; all
// waves confirm own loads, then barrier => granule complete], stage granule g+2,
// 12 ds_read_b128, 16 MFMA (setprio-wrapped). Loads for g+1/g+2 stay in flight
// ACROSS the barrier (T4 counted-vmcnt). Swizzle key (r&3)^((r>>2)&3) -> 2-way max.
// C/D layout (32x32): col=lane&31, row=(r&3)+8*(r>>2)+4*(lane>>5)  [m74/m101].

template <typename CT>
__global__ __launch_bounds__(512, 2) void gemm_ring(
    const f16* __restrict__ A, int lda,
    const f16* __restrict__ Bm, int ldb,
    CT* __restrict__ C, int ldc, int K, int nxt) {
  extern __shared__ f16 smem[];  // slot s: A at s*16384, B at s*16384+8192 (halfs)
  const int tid = threadIdx.x;
  const int lane = tid & 63;
  const int wid = tid >> 6;
  const int wr = wid >> 2;        // 0..1
  const int wc = wid & 3;         // 0..3
  const int r32 = lane & 31;
  const int khalf = lane >> 5;    // 0..1
  const int key = (r32 & 3) ^ ((r32 >> 2) & 3);

  const int nwg = gridDim.x;
  const int id = blockIdx.x;
  const int swz = (id & 7) * (nwg >> 3) + (id >> 3);
  const int m0 = (swz / nxt) * 256;
  const int n0 = (swz % nxt) * 256;

  // staging: srow = tid>>2 (128 rows/instr), phys slot tid&3, inverse-swizzled src
  const int srow = tid >> 2;
  const int scol = ((tid & 3) ^ (srow & 3) ^ ((srow >> 2) & 3)) * 8;
  const int NG = K >> 5;

  f32x16 acc[4][2];
#pragma unroll
  for (int i = 0; i < 4; ++i)
#pragma unroll
    for (int j = 0; j < 2; ++j)
#pragma unroll
      for (int r = 0; r < 16; ++r) acc[i][j][r] = 0.f;

  auto stage = [&](int g) {
    f16* dst = smem + (g & 3) * 16384 + tid * 8;
    const f16* gA = A + (size_t)(m0 + srow) * lda + g * 32 + scol;
    const f16* gB = Bm + (size_t)(n0 + srow) * ldb + g * 32 + scol;
    gload_lds16(gA, dst);
    gload_lds16(gA + (size_t)128 * lda, dst + 4096);
    gload_lds16(gB, dst + 8192);
    gload_lds16(gB + (size_t)128 * ldb, dst + 12288);
  };

  stage(0);
  stage(1);

  for (int g = 0; g < NG; ++g) {
    if (g + 1 < NG)
      asm volatile("s_waitcnt vmcnt(4)" ::: "memory");
    else
      asm volatile("s_waitcnt vmcnt(0)" ::: "memory");
    __builtin_amdgcn_sched_barrier(0);
    __builtin_amdgcn_s_barrier();
    __builtin_amdgcn_sched_barrier(0);
    if (g + 2 < NG) stage(g + 2);

    const f16* sa = smem + (g & 3) * 16384 + (wr * 128) * 32;
    const f16* sb = smem + (g & 3) * 16384 + 8192 + (wc * 64) * 32;
    f16x8 af[4][2], bf[2][2];
#pragma unroll
    for (int mi = 0; mi < 4; ++mi)
#pragma unroll
      for (int k = 0; k < 2; ++k)
        af[mi][k] = *(const f16x8*)(sa + (mi * 32 + r32) * 32 +
                                    (((k * 2 + khalf) ^ key) * 8));
#pragma unroll
    for (int ni = 0; ni < 2; ++ni)
#pragma unroll
      for (int k = 0; k < 2; ++k)
        bf[ni][k] = *(const f16x8*)(sb + (ni * 32 + r32) * 32 +
                                    (((k * 2 + khalf) ^ key) * 8));

    __builtin_amdgcn_s_setprio(1);
#pragma unroll
    for (int k = 0; k < 2; ++k)
#pragma unroll
      for (int mi = 0; mi < 4; ++mi)
#pragma unroll
        for (int ni = 0; ni < 2; ++ni)
          acc[mi][ni] = __builtin_amdgcn_mfma_f32_32x32x16_f16(
              af[mi][k], bf[ni][k], acc[mi][ni], 0, 0, 0);
    __builtin_amdgcn_s_setprio(0);
  }

#pragma unroll
  for (int mi = 0; mi < 4; ++mi)
#pragma unroll
    for (int ni = 0; ni < 2; ++ni)
#pragma unroll
      for (int r = 0; r < 16; ++r) {
        int row = m0 + wr * 128 + mi * 32 + (r & 3) + ((r >> 2) * 8) + khalf * 4;
        int col = n0 + wc * 64 + ni * 32 + r32;
        C[(size_t)row * ldc + col] = (CT)acc[mi][ni][r];
      }
}

// ---------------- launch ----------------

extern "C" void kernel_launch(void* const* d_in, const int* in_sizes, int n_in,
                              void* d_out, int out_size, void* d_ws, size_t ws_size,
                              hipStream_t stream) {
  const float* input = (const float*)d_in[0];
  const float* Dmat = (const float*)d_in[1];
  const float* nu_log = (const float*)d_in[2];
  const float* theta_log = (const float*)d_in[3];
  const float* gamma_log = (const float*)d_in[4];
  const float* B_re = (const float*)d_in[5];
  const float* B_im = (const float*)d_in[6];
  const float* C_re = (const float*)d_in[7];
  const float* C_im = (const float*)d_in[8];
  float* y = (float*)d_out;

  char* ws = (char*)d_ws;
  size_t off = 0;
  auto alloc = [&](size_t bytes) {
    void* p = ws + off;
    off = (off + bytes + 255) & ~(size_t)255;
    return p;
  };
  float2* lam2 = (float2*)alloc(N_SZ * sizeof(float2));
  float2* lamL2 = (float2*)alloc(N_SZ * sizeof(float2));
  f16* W1 = (f16*)alloc((size_t)2 * N_SZ * DIN * 2);        // [1024][512] f16
  f16* W2 = (f16*)alloc((size_t)DOUT * 1536 * 2);           // [512][1536] f16
  f16* A2 = (f16*)alloc((size_t)M_SZ * 1536 * 2);           // [M][re|im|in] f16
  f16* Bu = (f16*)alloc((size_t)M_SZ * 2 * N_SZ * 2);       // [M][1024] f16 (re,im)
  float2* S = (float2*)alloc((size_t)B_SZ * NCHUNK * N_SZ * sizeof(float2));
  float2* Carry = (float2*)alloc((size_t)B_SZ * NCHUNK * N_SZ * sizeof(float2));

  const int shmem = 131072;
  {
    auto* g16 = gemm_ring<f16>;
    auto* g32 = gemm_ring<float>;
    hipFuncSetAttribute((const void*)g16,
                        hipFuncAttributeMaxDynamicSharedMemorySize, shmem);
    hipFuncSetAttribute((const void*)g32,
                        hipFuncAttributeMaxDynamicSharedMemorySize, shmem);
  }

  prep_all<<<13314, 256, 0, stream>>>(nu_log, theta_log, gamma_log, B_re, B_im,
                                      C_re, C_im, Dmat, input, lam2, lamL2, W1, W2, A2);

  // Bu = input_f16 @ W1^T   (A = A2 cols [1024,1536), lda=1536)
  gemm_ring<f16><<<512, 512, shmem, stream>>>(A2 + 1024, 1536, W1, 512, Bu, 1024, 512, 4);

  scan_a<<<(B_SZ * NCHUNK * N_SZ) / 256, 256, 0, stream>>>(Bu, lam2, S);
  scan_b<<<(B_SZ * N_SZ) / 256, 256, 0, stream>>>(S, lamL2, Carry);
  scan_c<<<(B_SZ * NCHUNK * N_SZ) / 256, 256, 0, stream>>>(Bu, lam2, Carry, A2);

  // y = [s_re | s_im | in] @ [C_re | -C_im | D]^T
  gemm_ring<float><<<256, 512, shmem, stream>>>(A2, 1536, W2, 1536, y, 512, 1536, 2);
}